// Round 9
// baseline (495.698 us; speedup 1.0000x reference)
//
#include <hip/hip_runtime.h>

#define N_NODES   100000
#define N_EDGES   1600000
#define F         128
#define N_CLASSES 47

#define NBKT      256
#define GDIV2     391            // nodes per bucket (391*256 = 100096 >= 100000)
#define BCAP      7000           // staged capacity per bucket (Poisson mean 6250, +9.5 sd)
#define CAP       64             // col slab capacity per node (Poisson(16): P(>64)~1e-20)
#define EPT       16             // edges per thread in partition (512 threads)
#define PART_T    512
#define EPB       (PART_T * EPT) // 8192 edges per block
#define PART_B    ((N_EDGES + EPB - 1) / EPB)

typedef unsigned int uint32;

typedef short  v8s __attribute__((ext_vector_type(8)));   // 8 x bf16 (MFMA A/B frag)
typedef float  v4f __attribute__((ext_vector_type(4)));   // MFMA C/D frag

// bf16 helpers (RNE)
__device__ __forceinline__ uint32 f2bf(float f) {
    uint32 u = __float_as_uint(f);
    return (u + 0x7FFFu + ((u >> 16) & 1u)) >> 16;
}
__device__ __forceinline__ float bfl(uint32 u) { return __uint_as_float(u << 16); }
__device__ __forceinline__ float bfh(uint32 u) { return __uint_as_float(u & 0xFFFF0000u); }

// ---------------- phase A: bin edges into 256 node-range buckets ----------------

__global__ __launch_bounds__(512)
void partition256_kernel(const int* __restrict__ src, const int* __restrict__ dst,
                         int* __restrict__ gcnt, int2* __restrict__ staged) {
    __shared__ int hist[NBKT];
    __shared__ int gbase[NBKT];
    const int tid = threadIdx.x;
    const int e0  = blockIdx.x * EPB;

    if (tid < NBKT) hist[tid] = 0;
    __syncthreads();

    int mys[EPT], myd[EPT];
    #pragma unroll
    for (int i = 0; i < EPT; ++i) {
        int e = e0 + i * PART_T + tid;
        bool val = (e < N_EDGES);
        mys[i] = val ? src[e] : 0;
        myd[i] = val ? dst[e] : -1;
        if (val) atomicAdd(&hist[myd[i] / GDIV2], 1);     // LDS atomic
    }
    __syncthreads();

    if (tid < NBKT) gbase[tid] = atomicAdd(&gcnt[tid], hist[tid]);  // 1 global atomic/bucket/block
    __syncthreads();
    if (tid < NBKT) hist[tid] = 0;                        // reuse as cursor
    __syncthreads();

    #pragma unroll
    for (int i = 0; i < EPT; ++i) {
        if (myd[i] >= 0) {
            int b = myd[i] / GDIV2;
            int r = atomicAdd(&hist[b], 1);               // LDS cursor rank
            int idx = gbase[b] + r;
            if (idx < BCAP)
                staged[(size_t)b * BCAP + idx] = make_int2(mys[i], myd[i]);
        }
    }
}

// ---------------- phase B: per-bucket scatter with LDS counters ----------------

__global__ __launch_bounds__(512)
void bucket_scatter_kernel(const int2* __restrict__ staged, const int* __restrict__ gcnt,
                           int* __restrict__ fillc, float* __restrict__ rdeg,
                           int* __restrict__ col) {
    __shared__ int cnt[GDIV2];
    const int b     = blockIdx.x;
    const int tid   = threadIdx.x;
    const int node0 = b * GDIV2;

    for (int i = tid; i < GDIV2; i += 512) cnt[i] = 0;
    __syncthreads();

    const int n = min(gcnt[b], BCAP);
    const int2* sp = staged + (size_t)b * BCAP;
    for (int i = tid; i < n; i += 512) {
        int2 sd = sp[i];
        int c = atomicAdd(&cnt[sd.y - node0], 1);         // LDS atomic
        if (c < CAP) col[(size_t)sd.y * CAP + c] = sd.x;
    }
    __syncthreads();

    for (int i = tid; i < GDIV2; i += 512) {
        int v = node0 + i;
        if (v < N_NODES) {
            int d = min(cnt[i], CAP);
            fillc[v] = d;
            rdeg[v]  = 1.0f / (float)max(d, 1);
        }
    }
}

// ---------------- merged weight pre-pack ----------------

__global__ void pack_all_kernel(const float* __restrict__ Wn0, const float* __restrict__ Ws0,
                                const float* __restrict__ Wn1, const float* __restrict__ Ws1,
                                const float* __restrict__ Wn2, const float* __restrict__ Ws2,
                                unsigned short* __restrict__ wf0, unsigned short* __restrict__ wf1,
                                unsigned short* __restrict__ wf2n, unsigned short* __restrict__ wf2s) {
    const int blk  = blockIdx.x;
    const int lane = threadIdx.x;          // 64
    const int quad = lane >> 4;

    if (blk < 128) {                       // dual pack, K=256 (8 k-tiles)
        const float* Wn = (blk < 64) ? Wn0 : Wn1;
        const float* Ws = (blk < 64) ? Ws0 : Ws1;
        unsigned short* wfrag = (blk < 64) ? wf0 : wf1;
        int tile = blk & 63;
        int kt   = tile & 7;
        int mt   = tile >> 3;
        int m    = mt * 16 + (lane & 15);
        uint32 packed[4];
        #pragma unroll
        for (int jj = 0; jj < 4; ++jj) {
            uint32 lo = 0, hi = 0;
            #pragma unroll
            for (int b = 0; b < 2; ++b) {
                int k = kt * 32 + quad * 8 + jj * 2 + b;
                float w = (k < F) ? Wn[(size_t)k * F + m] : Ws[(size_t)(k - F) * F + m];
                if (b == 0) lo = f2bf(w); else hi = f2bf(w);
            }
            packed[jj] = lo | (hi << 16);
        }
        uint4 o = make_uint4(packed[0], packed[1], packed[2], packed[3]);
        *(uint4*)(wfrag + ((size_t)tile * 64 + lane) * 8) = o;
    } else {                               // single pack, K=128 (4 k-tiles), nout=47
        int bb = blk - 128;
        const float* W = (bb < 12) ? Wn2 : Ws2;
        unsigned short* wfrag = (bb < 12) ? wf2n : wf2s;
        int tile = (bb < 12) ? bb : (bb - 12);
        int kt   = tile & 3;
        int mt   = tile >> 2;
        int m    = mt * 16 + (lane & 15);
        uint32 packed[4];
        #pragma unroll
        for (int jj = 0; jj < 4; ++jj) {
            uint32 lo = 0, hi = 0;
            #pragma unroll
            for (int b = 0; b < 2; ++b) {
                int k = kt * 32 + quad * 8 + jj * 2 + b;
                float w = (m < N_CLASSES) ? W[(size_t)k * N_CLASSES + m] : 0.f;
                if (b == 0) lo = f2bf(w); else hi = f2bf(w);
            }
            packed[jj] = lo | (hi << 16);
        }
        uint4 o = make_uint4(packed[0], packed[1], packed[2], packed[3]);
        *(uint4*)(wfrag + ((size_t)tile * 64 + lane) * 8) = o;
    }
}

// ---------------- embedding gather: fp32 embed -> bf16 h ----------------

__global__ void gather_embed_kernel(const float* __restrict__ embed,
                                    const int* __restrict__ idx,
                                    unsigned short* __restrict__ h) {
    int i = blockIdx.x * blockDim.x + threadIdx.x;
    const int TOTAL = N_NODES * (F / 4);
    if (i < TOTAL) {
        int node = i >> 5;
        int c4 = i & 31;
        float4 v = ((const float4*)(embed + (size_t)idx[node] * F))[c4];
        uint2 o;
        o.x = f2bf(v.x) | (f2bf(v.y) << 16);
        o.y = f2bf(v.z) | (f2bf(v.w) << 16);
        ((uint2*)(h + (size_t)node * F))[c4] = o;
    }
}

// ---------------- fused layer (layers 0/1), wave-autonomous (NO barriers) ----------------
// Each wave owns 8 nodes: gathers them into its private LDS slice, then runs
// the [mean|h] @ Wcat GEMM for those 8 rows itself (B rows nn&7, rows 8-15
// duplicated, stores masked to nn<8). Same-wave LDS write->read is ordered by
// the DS pipe; no __syncthreads -> no inter-wave idle at phase boundaries.
// EMIT_HN2 (layer 1): epilogue writes post-relu bf16 rows into the freed LDS
// slice and computes hn2 = out @ Wn2 in-place (kills the gemm_hn2 pass).

template<bool EMIT_HN2>
__global__ __launch_bounds__(256)
void fused_layer_kernel(const unsigned short* __restrict__ h,
                        const int* __restrict__ deg,
                        const int* __restrict__ col,
                        const float* __restrict__ rdeg,
                        const unsigned short* __restrict__ wfrag,
                        const float* __restrict__ bias,
                        unsigned short* __restrict__ out,
                        const unsigned short* __restrict__ wfrag2,
                        unsigned short* __restrict__ hn2) {
    __shared__ unsigned short Bm[32][136];   // 4 wave-private 8x128 slices, +8 pad

    const int wv   = threadIdx.x >> 6;
    const int lane = threadIdx.x & 63;
    const int sub  = lane >> 4;
    const int li   = lane & 15;
    const int base = blockIdx.x * 32;        // grid 3125 * 32 = 100000 exact
    const int nbase = base + wv * 8;

    const uint4* hp4 = (const uint4*)h;

    // ---- phase 1: aggregate 8 nodes (4-deep independent loads) ----
    for (int j = 0; j < 8; ++j) {
        const int v   = nbase + j;
        const int beg = v * CAP;
        const int end = beg + deg[v];
        const int dmax = max(end - 1, beg);

        float a0 = 0.f, a1 = 0.f, a2 = 0.f, a3 = 0.f;
        float a4 = 0.f, a5 = 0.f, a6 = 0.f, a7 = 0.f;

        #pragma unroll 1
        for (int p = beg; p < end; p += 16) {
            const int e0i = p + sub, e1i = p + 4 + sub, e2i = p + 8 + sub, e3i = p + 12 + sub;
            int u0 = col[min(e0i, dmax)];
            int u1 = col[min(e1i, dmax)];
            int u2 = col[min(e2i, dmax)];
            int u3 = col[min(e3i, dmax)];
            uint4 x0 = hp4[(size_t)u0 * 16 + li];
            uint4 x1 = hp4[(size_t)u1 * 16 + li];
            uint4 x2 = hp4[(size_t)u2 * 16 + li];
            uint4 x3 = hp4[(size_t)u3 * 16 + li];
            if (e0i < end) {
                a0 += bfl(x0.x); a1 += bfh(x0.x); a2 += bfl(x0.y); a3 += bfh(x0.y);
                a4 += bfl(x0.z); a5 += bfh(x0.z); a6 += bfl(x0.w); a7 += bfh(x0.w);
            }
            if (e1i < end) {
                a0 += bfl(x1.x); a1 += bfh(x1.x); a2 += bfl(x1.y); a3 += bfh(x1.y);
                a4 += bfl(x1.z); a5 += bfh(x1.z); a6 += bfl(x1.w); a7 += bfh(x1.w);
            }
            if (e2i < end) {
                a0 += bfl(x2.x); a1 += bfh(x2.x); a2 += bfl(x2.y); a3 += bfh(x2.y);
                a4 += bfl(x2.z); a5 += bfh(x2.z); a6 += bfl(x2.w); a7 += bfh(x2.w);
            }
            if (e3i < end) {
                a0 += bfl(x3.x); a1 += bfh(x3.x); a2 += bfl(x3.y); a3 += bfh(x3.y);
                a4 += bfl(x3.z); a5 += bfh(x3.z); a6 += bfl(x3.w); a7 += bfh(x3.w);
            }
        }

        #pragma unroll
        for (int m = 16; m <= 32; m <<= 1) {
            a0 += __shfl_xor(a0, m, 64);
            a1 += __shfl_xor(a1, m, 64);
            a2 += __shfl_xor(a2, m, 64);
            a3 += __shfl_xor(a3, m, 64);
            a4 += __shfl_xor(a4, m, 64);
            a5 += __shfl_xor(a5, m, 64);
            a6 += __shfl_xor(a6, m, 64);
            a7 += __shfl_xor(a7, m, 64);
        }

        if (sub == 0) {
            const float r = rdeg[v];
            uint4 o;
            o.x = f2bf(a0 * r) | (f2bf(a1 * r) << 16);
            o.y = f2bf(a2 * r) | (f2bf(a3 * r) << 16);
            o.z = f2bf(a4 * r) | (f2bf(a5 * r) << 16);
            o.w = f2bf(a6 * r) | (f2bf(a7 * r) << 16);
            *(uint4*)&Bm[wv * 8 + j][li * 8] = o;
        }
    }
    // no __syncthreads: same-wave DS ordering suffices

    // ---- phase 2: this wave's 8-row GEMM (B rows nn&7; nn>=8 duplicates) ----
    const int quad = sub;
    const int nn   = li;
    const int rn   = nn & 7;
    const int node = nbase + rn;
    const size_t rs = (size_t)node * F;

    v4f acc[8];
    #pragma unroll
    for (int mt = 0; mt < 8; ++mt) acc[mt] = (v4f)0.f;

    #pragma unroll
    for (int kt = 0; kt < 8; ++kt) {
        const int koff = (kt & 3) * 32 + quad * 8;
        v8s b = (kt < 4) ? *(const v8s*)&Bm[wv * 8 + rn][koff]
                         : *(const v8s*)(h + rs + koff);
        #pragma unroll
        for (int mt = 0; mt < 8; ++mt) {
            v8s a = *(const v8s*)(wfrag + ((size_t)(mt * 8 + kt) * 64 + lane) * 8);
            acc[mt] = __builtin_amdgcn_mfma_f32_16x16x32_bf16(a, b, acc[mt], 0, 0, 0);
        }
    }

    uint2 obuf[8];
    #pragma unroll
    for (int mt = 0; mt < 8; ++mt) {
        const int m0 = mt * 16 + quad * 4;
        const float4 bb = *(const float4*)(bias + m0);
        float x0 = fmaxf(acc[mt][0] + bb.x, 0.f);
        float x1 = fmaxf(acc[mt][1] + bb.y, 0.f);
        float x2 = fmaxf(acc[mt][2] + bb.z, 0.f);
        float x3 = fmaxf(acc[mt][3] + bb.w, 0.f);
        uint2 o;
        o.x = f2bf(x0) | (f2bf(x1) << 16);
        o.y = f2bf(x2) | (f2bf(x3) << 16);
        obuf[mt] = o;
        if (nn < 8) *(uint2*)(out + rs + m0) = o;
    }

    if (EMIT_HN2) {
        // write post-relu rows into the freed LDS slice (only nn<8 lanes)
        if (nn < 8) {
            #pragma unroll
            for (int mt = 0; mt < 8; ++mt)
                *(uint2*)&Bm[wv * 8 + rn][mt * 16 + quad * 4] = obuf[mt];
        }
        // hn2 = out @ Wn2 for this wave's 8 rows (same-wave DS ordering)
        v4f acc2[3];
        acc2[0] = (v4f)0.f; acc2[1] = (v4f)0.f; acc2[2] = (v4f)0.f;
        #pragma unroll
        for (int kt = 0; kt < 4; ++kt) {
            const int koff = kt * 32 + quad * 8;
            v8s b2 = *(const v8s*)&Bm[wv * 8 + rn][koff];
            #pragma unroll
            for (int mt = 0; mt < 3; ++mt) {
                v8s a2 = *(const v8s*)(wfrag2 + ((size_t)(mt * 4 + kt) * 64 + lane) * 8);
                acc2[mt] = __builtin_amdgcn_mfma_f32_16x16x32_bf16(a2, b2, acc2[mt], 0, 0, 0);
            }
        }
        if (nn < 8) {
            #pragma unroll
            for (int mt = 0; mt < 3; ++mt) {
                const int m0 = mt * 16 + quad * 4;   // 0..44
                uint2 o;
                o.x = f2bf(acc2[mt][0]) | (f2bf(acc2[mt][1]) << 16);
                o.y = f2bf(acc2[mt][2]) | (f2bf(acc2[mt][3]) << 16);
                *(uint2*)(hn2 + (size_t)node * 64 + m0) = o;
            }
        }
    }
}

// ---------------- fused layer 2, wave-autonomous: agg48(hn2) -> out = mean2 + h@Ws2 + b2 ----

__global__ __launch_bounds__(256)
void fused_final_kernel(const unsigned short* __restrict__ hn,
                        const int* __restrict__ deg,
                        const int* __restrict__ col,
                        const float* __restrict__ rdeg,
                        const unsigned short* __restrict__ h,
                        const unsigned short* __restrict__ wfrag,
                        const float* __restrict__ bias,
                        float* __restrict__ out) {
    __shared__ unsigned short M2[32][72];    // 4 wave-private 8x64 slices, +8 pad

    const int wv   = threadIdx.x >> 6;
    const int lane = threadIdx.x & 63;
    const int sub8 = lane >> 3;
    const int li8  = lane & 7;
    const int base = blockIdx.x * 32;
    const int nbase = base + wv * 8;

    const uint4* hp4 = (const uint4*)hn;     // 8 uint4 per 128B row

    // ---- phase 1: 48-wide aggregate, 8 nodes per wave ----
    for (int j = 0; j < 8; ++j) {
        const int v   = nbase + j;
        const int beg = v * CAP;
        const int end = beg + deg[v];
        const int dmax = max(end - 1, beg);

        float a0 = 0.f, a1 = 0.f, a2 = 0.f, a3 = 0.f;
        float a4 = 0.f, a5 = 0.f, a6 = 0.f, a7 = 0.f;

        #pragma unroll 1
        for (int p = beg; p < end; p += 16) {
            const int e0i = p + sub8, e1i = p + 8 + sub8;
            int u0 = col[min(e0i, dmax)];
            int u1 = col[min(e1i, dmax)];
            uint4 x0 = hp4[(size_t)u0 * 8 + li8];
            uint4 x1 = hp4[(size_t)u1 * 8 + li8];
            if (e0i < end) {
                a0 += bfl(x0.x); a1 += bfh(x0.x); a2 += bfl(x0.y); a3 += bfh(x0.y);
                a4 += bfl(x0.z); a5 += bfh(x0.z); a6 += bfl(x0.w); a7 += bfh(x0.w);
            }
            if (e1i < end) {
                a0 += bfl(x1.x); a1 += bfh(x1.x); a2 += bfl(x1.y); a3 += bfh(x1.y);
                a4 += bfl(x1.z); a5 += bfh(x1.z); a6 += bfl(x1.w); a7 += bfh(x1.w);
            }
        }

        #pragma unroll
        for (int m = 8; m <= 32; m <<= 1) {
            a0 += __shfl_xor(a0, m, 64);
            a1 += __shfl_xor(a1, m, 64);
            a2 += __shfl_xor(a2, m, 64);
            a3 += __shfl_xor(a3, m, 64);
            a4 += __shfl_xor(a4, m, 64);
            a5 += __shfl_xor(a5, m, 64);
            a6 += __shfl_xor(a6, m, 64);
            a7 += __shfl_xor(a7, m, 64);
        }

        if (sub8 == 0) {
            const float r = rdeg[v];
            uint4 o;
            o.x = f2bf(a0 * r) | (f2bf(a1 * r) << 16);
            o.y = f2bf(a2 * r) | (f2bf(a3 * r) << 16);
            o.z = f2bf(a4 * r) | (f2bf(a5 * r) << 16);
            o.w = f2bf(a6 * r) | (f2bf(a7 * r) << 16);
            *(uint4*)&M2[wv * 8 + j][li8 * 8] = o;
        }
    }
    // no __syncthreads

    // ---- phase 2: out = mean2 + h @ Ws2 + b2 for this wave's 8 rows ----
    const int quad = lane >> 4;
    const int nn   = lane & 15;
    const int rn   = nn & 7;
    const int node = nbase + rn;
    const size_t rs = (size_t)node * F;

    v4f acc[3];
    acc[0] = (v4f)0.f; acc[1] = (v4f)0.f; acc[2] = (v4f)0.f;

    #pragma unroll
    for (int kt = 0; kt < 4; ++kt) {
        const int koff = kt * 32 + quad * 8;
        v8s b = *(const v8s*)(h + rs + koff);
        #pragma unroll
        for (int mt = 0; mt < 3; ++mt) {
            v8s a = *(const v8s*)(wfrag + ((size_t)(mt * 4 + kt) * 64 + lane) * 8);
            acc[mt] = __builtin_amdgcn_mfma_f32_16x16x32_bf16(a, b, acc[mt], 0, 0, 0);
        }
    }

    if (nn < 8) {
        #pragma unroll
        for (int mt = 0; mt < 3; ++mt) {
            const int m0 = mt * 16 + quad * 4;   // 0..44
            uint2 mv = *(const uint2*)&M2[wv * 8 + rn][m0];
            float mf[4] = { bfl(mv.x), bfh(mv.x), bfl(mv.y), bfh(mv.y) };
            #pragma unroll
            for (int r = 0; r < 4; ++r) {
                int m = m0 + r;
                if (m < N_CLASSES)
                    out[(size_t)node * N_CLASSES + m] = acc[mt][r] + bias[m] + mf[r];
            }
        }
    }
}

// ---------------- launch ----------------

extern "C" void kernel_launch(void* const* d_in, const int* in_sizes, int n_in,
                              void* d_out, int out_size, void* d_ws, size_t ws_size,
                              hipStream_t stream) {
    const float* embed = (const float*)d_in[0];
    const float* Ws0   = (const float*)d_in[1];
    const float* Wn0   = (const float*)d_in[2];
    const float* b0    = (const float*)d_in[3];
    const float* Ws1   = (const float*)d_in[4];
    const float* Wn1   = (const float*)d_in[5];
    const float* b1    = (const float*)d_in[6];
    const float* Ws2   = (const float*)d_in[7];
    const float* Wn2   = (const float*)d_in[8];
    const float* b2    = (const float*)d_in[9];
    const int* input_nodes = (const int*)d_in[10];
    const int* src     = (const int*)d_in[11];
    const int* dst     = (const int*)d_in[12];
    float* out = (float*)d_out;

    char* ws = (char*)d_ws;
    size_t off = 0;
    auto alloc = [&](size_t bytes) -> void* {
        void* p = ws + off;
        off += (bytes + 255) & ~(size_t)255;
        return p;
    };
    int*            fillc    = (int*)           alloc(sizeof(int)   * N_NODES);
    float*          rdeg     = (float*)         alloc(sizeof(float) * N_NODES);
    int*            col      = (int*)           alloc(sizeof(int)   * (size_t)N_NODES * CAP);
    int*            gcnt     = (int*)           alloc(sizeof(int)   * NBKT);
    int2*           staged   = (int2*)          alloc(sizeof(int2)  * (size_t)NBKT * BCAP);
    unsigned short* h_a      = (unsigned short*)alloc(2 * (size_t)N_NODES * F);
    unsigned short* h_b      = (unsigned short*)alloc(2 * (size_t)N_NODES * F);
    unsigned short* wf0      = (unsigned short*)alloc(2 * 64 * 512);
    unsigned short* wf1      = (unsigned short*)alloc(2 * 64 * 512);
    unsigned short* wf2n     = (unsigned short*)alloc(2 * 12 * 512);
    unsigned short* wf2s     = (unsigned short*)alloc(2 * 12 * 512);
    (void)ws_size; (void)n_in; (void)in_sizes; (void)out_size;

    // hn2 (100000 x 64 bf16 = 12.8MB) aliases staged (14.3MB, dead after scatter)
    unsigned short* hn2 = (unsigned short*)staged;

    hipMemsetAsync(gcnt, 0, sizeof(int) * NBKT, stream);

    partition256_kernel<<<PART_B, PART_T, 0, stream>>>(src, dst, gcnt, staged);
    bucket_scatter_kernel<<<NBKT, 512, 0, stream>>>(staged, gcnt, fillc, rdeg, col);

    pack_all_kernel<<<152, 64, 0, stream>>>(Wn0, Ws0, Wn1, Ws1, Wn2, Ws2, wf0, wf1, wf2n, wf2s);

    gather_embed_kernel<<<(N_NODES * (F / 4) + 255) / 256, 256, 0, stream>>>(embed, input_nodes, h_a);

    const int FUSED_B = N_NODES / 32;        // 3125, exact

    // layer 0: h_a -> h_b
    fused_layer_kernel<false><<<FUSED_B, 256, 0, stream>>>(h_a, fillc, col, rdeg, wf0, b0, h_b, wf2n, hn2);
    // layer 1: h_b -> h_a, epilogue also emits hn2 = relu_out @ Wn2
    fused_layer_kernel<true><<<FUSED_B, 256, 0, stream>>>(h_b, fillc, col, rdeg, wf1, b1, h_a, wf2n, hn2);
    // layer 2: mean2 = agg48(hn2) in LDS; out = mean2 + h_a @ Ws2 + b2
    fused_final_kernel<<<FUSED_B, 256, 0, stream>>>(hn2, fillc, col, rdeg, h_a, wf2s, b2, out);
}

// Round 10
// 363.839 us; speedup vs baseline: 1.3624x; 1.3624x over previous
//
#include <hip/hip_runtime.h>

#define N_NODES   100000
#define N_EDGES   1600000
#define F         128
#define N_CLASSES 47

#define NBKT      256
#define GDIV2     391            // nodes per bucket (391*256 = 100096 >= 100000)
#define BCAP      7000           // staged capacity per bucket (Poisson mean 6250, +9.5 sd)
#define CAP       64             // col slab capacity per node (Poisson(16): P(>64)~1e-20)
#define EPT       16             // edges per thread in partition (512 threads)
#define PART_T    512
#define EPB       (PART_T * EPT) // 8192 edges per block
#define PART_B    ((N_EDGES + EPB - 1) / EPB)
#define EMB_B     ((N_NODES * 32 + 511) / 512)   // embed blocks appended to partition grid
#define PACK_B    152                            // pack blocks appended to scatter grid

typedef unsigned int uint32;

typedef short  v8s __attribute__((ext_vector_type(8)));   // 8 x bf16 (MFMA A/B frag)
typedef float  v4f __attribute__((ext_vector_type(4)));   // MFMA C/D frag

// bf16 helpers (RNE)
__device__ __forceinline__ uint32 f2bf(float f) {
    uint32 u = __float_as_uint(f);
    return (u + 0x7FFFu + ((u >> 16) & 1u)) >> 16;
}
__device__ __forceinline__ float bfl(uint32 u) { return __uint_as_float(u << 16); }
__device__ __forceinline__ float bfh(uint32 u) { return __uint_as_float(u & 0xFFFF0000u); }

// ---------------- prologue 1: partition (blocks < PART_B) + embed gather (rest) ----------------
// The two jobs are independent; merging removes one launch gap and overlaps
// the streaming embed conversion with partition's LDS-histogram phase.

__global__ __launch_bounds__(512)
void prologue1_kernel(const int* __restrict__ src, const int* __restrict__ dst,
                      int* __restrict__ gcnt, int2* __restrict__ staged,
                      const float* __restrict__ embed, const int* __restrict__ idx,
                      unsigned short* __restrict__ h) {
    const int tid = threadIdx.x;

    if (blockIdx.x >= PART_B) {
        // ---- embed gather: fp32 embed -> bf16 h ----
        int i = (blockIdx.x - PART_B) * 512 + tid;
        const int TOTAL = N_NODES * (F / 4);
        if (i < TOTAL) {
            int node = i >> 5;
            int c4 = i & 31;
            float4 v = ((const float4*)(embed + (size_t)idx[node] * F))[c4];
            uint2 o;
            o.x = f2bf(v.x) | (f2bf(v.y) << 16);
            o.y = f2bf(v.z) | (f2bf(v.w) << 16);
            ((uint2*)(h + (size_t)node * F))[c4] = o;
        }
        return;
    }

    // ---- partition: bin edges into 256 node-range buckets ----
    __shared__ int hist[NBKT];
    __shared__ int gbase[NBKT];
    const int e0 = blockIdx.x * EPB;

    if (tid < NBKT) hist[tid] = 0;
    __syncthreads();

    int mys[EPT], myd[EPT];
    #pragma unroll
    for (int i = 0; i < EPT; ++i) {
        int e = e0 + i * PART_T + tid;
        bool val = (e < N_EDGES);
        mys[i] = val ? src[e] : 0;
        myd[i] = val ? dst[e] : -1;
        if (val) atomicAdd(&hist[myd[i] / GDIV2], 1);     // LDS atomic
    }
    __syncthreads();

    if (tid < NBKT) gbase[tid] = atomicAdd(&gcnt[tid], hist[tid]);  // 1 global atomic/bucket/block
    __syncthreads();
    if (tid < NBKT) hist[tid] = 0;                        // reuse as cursor
    __syncthreads();

    #pragma unroll
    for (int i = 0; i < EPT; ++i) {
        if (myd[i] >= 0) {
            int b = myd[i] / GDIV2;
            int r = atomicAdd(&hist[b], 1);               // LDS cursor rank
            int idx2 = gbase[b] + r;
            if (idx2 < BCAP)
                staged[(size_t)b * BCAP + idx2] = make_int2(mys[i], myd[i]);
        }
    }
}

// ---------------- prologue 2: bucket scatter (blocks < NBKT) + weight pack (rest) ----------------

__global__ __launch_bounds__(512)
void prologue2_kernel(const int2* __restrict__ staged, const int* __restrict__ gcnt,
                      int* __restrict__ fillc, float* __restrict__ rdeg,
                      int* __restrict__ col,
                      const float* __restrict__ Wn0, const float* __restrict__ Ws0,
                      const float* __restrict__ Wn1, const float* __restrict__ Ws1,
                      const float* __restrict__ Wn2, const float* __restrict__ Ws2,
                      unsigned short* __restrict__ wf0, unsigned short* __restrict__ wf1,
                      unsigned short* __restrict__ wf2n, unsigned short* __restrict__ wf2s) {
    const int tid = threadIdx.x;

    if (blockIdx.x >= NBKT) {
        // ---- weight pack (first 64 lanes only) ----
        if (tid >= 64) return;
        const int blk  = blockIdx.x - NBKT;   // 0..151
        const int lane = tid;
        const int quad = lane >> 4;

        if (blk < 128) {                       // dual pack, K=256 (8 k-tiles)
            const float* Wn = (blk < 64) ? Wn0 : Wn1;
            const float* Ws = (blk < 64) ? Ws0 : Ws1;
            unsigned short* wfrag = (blk < 64) ? wf0 : wf1;
            int tile = blk & 63;
            int kt   = tile & 7;
            int mt   = tile >> 3;
            int m    = mt * 16 + (lane & 15);
            uint32 packed[4];
            #pragma unroll
            for (int jj = 0; jj < 4; ++jj) {
                uint32 lo = 0, hi = 0;
                #pragma unroll
                for (int b = 0; b < 2; ++b) {
                    int k = kt * 32 + quad * 8 + jj * 2 + b;
                    float w = (k < F) ? Wn[(size_t)k * F + m] : Ws[(size_t)(k - F) * F + m];
                    if (b == 0) lo = f2bf(w); else hi = f2bf(w);
                }
                packed[jj] = lo | (hi << 16);
            }
            uint4 o = make_uint4(packed[0], packed[1], packed[2], packed[3]);
            *(uint4*)(wfrag + ((size_t)tile * 64 + lane) * 8) = o;
        } else {                               // single pack, K=128 (4 k-tiles), nout=47
            int bb = blk - 128;
            const float* W = (bb < 12) ? Wn2 : Ws2;
            unsigned short* wfrag = (bb < 12) ? wf2n : wf2s;
            int tile = (bb < 12) ? bb : (bb - 12);
            int kt   = tile & 3;
            int mt   = tile >> 2;
            int m    = mt * 16 + (lane & 15);
            uint32 packed[4];
            #pragma unroll
            for (int jj = 0; jj < 4; ++jj) {
                uint32 lo = 0, hi = 0;
                #pragma unroll
                for (int b = 0; b < 2; ++b) {
                    int k = kt * 32 + quad * 8 + jj * 2 + b;
                    float w = (m < N_CLASSES) ? W[(size_t)k * N_CLASSES + m] : 0.f;
                    if (b == 0) lo = f2bf(w); else hi = f2bf(w);
                }
                packed[jj] = lo | (hi << 16);
            }
            uint4 o = make_uint4(packed[0], packed[1], packed[2], packed[3]);
            *(uint4*)(wfrag + ((size_t)tile * 64 + lane) * 8) = o;
        }
        return;
    }

    // ---- bucket scatter with LDS counters ----
    __shared__ int cnt[GDIV2];
    const int b     = blockIdx.x;
    const int node0 = b * GDIV2;

    for (int i = tid; i < GDIV2; i += 512) cnt[i] = 0;
    __syncthreads();

    const int n = min(gcnt[b], BCAP);
    const int2* sp = staged + (size_t)b * BCAP;
    for (int i = tid; i < n; i += 512) {
        int2 sd = sp[i];
        int c = atomicAdd(&cnt[sd.y - node0], 1);         // LDS atomic
        if (c < CAP) col[(size_t)sd.y * CAP + c] = sd.x;
    }
    __syncthreads();

    for (int i = tid; i < GDIV2; i += 512) {
        int v = node0 + i;
        if (v < N_NODES) {
            int d = min(cnt[i], CAP);
            fillc[v] = d;
            rdeg[v]  = 1.0f / (float)max(d, 1);
        }
    }
}

// ---------------- fused layer (layers 0/1): aggregate 32 nodes -> LDS mean tile,
// then out = [mean|h] @ Wcat + b (+relu). Serial prefetch-chain gather (r7,
// measured best). Barrier between phases; each wave does 2 m-tiles in phase 2.

__global__ __launch_bounds__(256)
void fused_layer_kernel(const unsigned short* __restrict__ h,
                        const int* __restrict__ deg,
                        const int* __restrict__ col,
                        const float* __restrict__ rdeg,
                        const unsigned short* __restrict__ wfrag,
                        const float* __restrict__ bias,
                        unsigned short* __restrict__ out) {
    __shared__ unsigned short Bm[32][136];   // 32 x 128 mean tile, +8 pad

    const int wv   = threadIdx.x >> 6;
    const int lane = threadIdx.x & 63;
    const int sub  = lane >> 4;
    const int li   = lane & 15;
    const int base = blockIdx.x * 32;        // grid 3125 * 32 = 100000 exact

    const uint4* hp4 = (const uint4*)h;

    // ---- phase 1: aggregate 8 nodes per wave ----
    for (int j = 0; j < 8; ++j) {
        const int v   = base + wv * 8 + j;
        const int beg = v * CAP;
        const int end = beg + deg[v];
        const int dmax = max(end - 1, beg);

        float a0 = 0.f, a1 = 0.f, a2 = 0.f, a3 = 0.f;
        float a4 = 0.f, a5 = 0.f, a6 = 0.f, a7 = 0.f;

        int p = beg;
        int u = col[min(p + sub, dmax)];
        #pragma unroll 2
        for (; p + 4 <= end; p += 4) {
            int un = col[min(p + 4 + sub, dmax)];
            uint4 x = hp4[(size_t)u * 16 + li];
            a0 += bfl(x.x); a1 += bfh(x.x);
            a2 += bfl(x.y); a3 += bfh(x.y);
            a4 += bfl(x.z); a5 += bfh(x.z);
            a6 += bfl(x.w); a7 += bfh(x.w);
            u = un;
        }
        if (p + sub < end) {
            uint4 x = hp4[(size_t)u * 16 + li];
            a0 += bfl(x.x); a1 += bfh(x.x);
            a2 += bfl(x.y); a3 += bfh(x.y);
            a4 += bfl(x.z); a5 += bfh(x.z);
            a6 += bfl(x.w); a7 += bfh(x.w);
        }

        #pragma unroll
        for (int m = 16; m <= 32; m <<= 1) {
            a0 += __shfl_xor(a0, m, 64);
            a1 += __shfl_xor(a1, m, 64);
            a2 += __shfl_xor(a2, m, 64);
            a3 += __shfl_xor(a3, m, 64);
            a4 += __shfl_xor(a4, m, 64);
            a5 += __shfl_xor(a5, m, 64);
            a6 += __shfl_xor(a6, m, 64);
            a7 += __shfl_xor(a7, m, 64);
        }

        if (sub == 0) {
            const float r = rdeg[v];
            uint4 o;
            o.x = f2bf(a0 * r) | (f2bf(a1 * r) << 16);
            o.y = f2bf(a2 * r) | (f2bf(a3 * r) << 16);
            o.z = f2bf(a4 * r) | (f2bf(a5 * r) << 16);
            o.w = f2bf(a6 * r) | (f2bf(a7 * r) << 16);
            *(uint4*)&Bm[wv * 8 + j][li * 8] = o;
        }
    }
    __syncthreads();

    // ---- phase 2: GEMM, wave wv handles m-tiles {2wv, 2wv+1} ----
    const int quad = sub;
    const int nn   = li;
    const size_t r0 = (size_t)(base + nn) * F;
    const size_t r1 = (size_t)(base + 16 + nn) * F;

    v4f acc[2][2];
    acc[0][0] = (v4f)0.f; acc[0][1] = (v4f)0.f;
    acc[1][0] = (v4f)0.f; acc[1][1] = (v4f)0.f;

    #pragma unroll
    for (int kt = 0; kt < 8; ++kt) {
        const int koff = (kt & 3) * 32 + quad * 8;
        v8s b0, b1;
        if (kt < 4) {
            b0 = *(const v8s*)&Bm[nn][koff];
            b1 = *(const v8s*)&Bm[nn + 16][koff];
        } else {
            b0 = *(const v8s*)(h + r0 + koff);
            b1 = *(const v8s*)(h + r1 + koff);
        }
        #pragma unroll
        for (int m2 = 0; m2 < 2; ++m2) {
            const int mt = wv * 2 + m2;
            v8s a = *(const v8s*)(wfrag + ((size_t)(mt * 8 + kt) * 64 + lane) * 8);
            acc[m2][0] = __builtin_amdgcn_mfma_f32_16x16x32_bf16(a, b0, acc[m2][0], 0, 0, 0);
            acc[m2][1] = __builtin_amdgcn_mfma_f32_16x16x32_bf16(a, b1, acc[m2][1], 0, 0, 0);
        }
    }

    #pragma unroll
    for (int m2 = 0; m2 < 2; ++m2) {
        const int m0 = (wv * 2 + m2) * 16 + quad * 4;
        const float4 bb = *(const float4*)(bias + m0);
        #pragma unroll
        for (int nt = 0; nt < 2; ++nt) {
            const int node = base + nt * 16 + nn;
            v4f a = acc[m2][nt];
            float x0 = fmaxf(a[0] + bb.x, 0.f);
            float x1 = fmaxf(a[1] + bb.y, 0.f);
            float x2 = fmaxf(a[2] + bb.z, 0.f);
            float x3 = fmaxf(a[3] + bb.w, 0.f);
            uint2 o;
            o.x = f2bf(x0) | (f2bf(x1) << 16);
            o.y = f2bf(x2) | (f2bf(x3) << 16);
            *(uint2*)(out + (size_t)node * F + m0) = o;
        }
    }
}

// ---------------- layer-2: hn2 = h @ Wn2 (bf16 out, row stride 64) ----------------

__global__ __launch_bounds__(256)
void gemm_hn2_kernel(const unsigned short* __restrict__ h,
                     const unsigned short* __restrict__ wfrag,
                     unsigned short* __restrict__ hn2) {
    const int lane = threadIdx.x & 63;
    const int wave = threadIdx.x >> 6;
    const int quad = lane >> 4;
    const int nn   = lane & 15;
    const int base = blockIdx.x * 128 + wave * 32;

    const int n0 = base + nn;
    const int n1 = base + 16 + nn;
    const size_t r0 = (size_t)min(n0, N_NODES - 1) * F;
    const size_t r1 = (size_t)min(n1, N_NODES - 1) * F;

    v4f acc[3][2];
    #pragma unroll
    for (int mt = 0; mt < 3; ++mt) { acc[mt][0] = (v4f)0.f; acc[mt][1] = (v4f)0.f; }

    #pragma unroll
    for (int kt = 0; kt < 4; ++kt) {
        const int koff = kt * 32 + quad * 8;
        v8s b0 = *(const v8s*)(h + r0 + koff);
        v8s b1 = *(const v8s*)(h + r1 + koff);
        #pragma unroll
        for (int mt = 0; mt < 3; ++mt) {
            v8s a = *(const v8s*)(wfrag + ((size_t)(mt * 4 + kt) * 64 + lane) * 8);
            acc[mt][0] = __builtin_amdgcn_mfma_f32_16x16x32_bf16(a, b0, acc[mt][0], 0, 0, 0);
            acc[mt][1] = __builtin_amdgcn_mfma_f32_16x16x32_bf16(a, b1, acc[mt][1], 0, 0, 0);
        }
    }

    #pragma unroll
    for (int mt = 0; mt < 3; ++mt) {
        const int m0 = mt * 16 + quad * 4;   // 0..47
        #pragma unroll
        for (int nt = 0; nt < 2; ++nt) {
            const int node = base + nt * 16 + nn;
            if (node >= N_NODES) continue;
            v4f a = acc[mt][nt];
            uint2 o;
            o.x = f2bf(a[0]) | (f2bf(a[1]) << 16);
            o.y = f2bf(a[2]) | (f2bf(a[3]) << 16);
            *(uint2*)(hn2 + (size_t)node * 64 + m0) = o;
        }
    }
}

// ---------------- fused layer 2: aggregate48(hn2) -> LDS, out = mean2 + h@Ws2 + b2 ----

__global__ __launch_bounds__(256)
void fused_final_kernel(const unsigned short* __restrict__ hn,
                        const int* __restrict__ deg,
                        const int* __restrict__ col,
                        const float* __restrict__ rdeg,
                        const unsigned short* __restrict__ h,
                        const unsigned short* __restrict__ wfrag,
                        const float* __restrict__ bias,
                        float* __restrict__ out) {
    __shared__ unsigned short M2[32][72];    // 32 x 64 mean2 tile, +8 pad

    const int wv   = threadIdx.x >> 6;
    const int lane = threadIdx.x & 63;
    const int sub8 = lane >> 3;
    const int li8  = lane & 7;
    const int base = blockIdx.x * 32;

    const uint4* hp4 = (const uint4*)hn;     // 8 uint4 per 128B row

    // ---- phase 1: 48-wide aggregate, 8 nodes per wave (serial chain) ----
    for (int j = 0; j < 8; ++j) {
        const int v   = base + wv * 8 + j;
        const int beg = v * CAP;
        const int end = beg + deg[v];
        const int dmax = max(end - 1, beg);

        float a0 = 0.f, a1 = 0.f, a2 = 0.f, a3 = 0.f;
        float a4 = 0.f, a5 = 0.f, a6 = 0.f, a7 = 0.f;

        int p = beg;
        int u = col[min(p + sub8, dmax)];
        #pragma unroll 2
        for (; p + 8 <= end; p += 8) {
            int un = col[min(p + 8 + sub8, dmax)];
            uint4 x = hp4[(size_t)u * 8 + li8];
            a0 += bfl(x.x); a1 += bfh(x.x);
            a2 += bfl(x.y); a3 += bfh(x.y);
            a4 += bfl(x.z); a5 += bfh(x.z);
            a6 += bfl(x.w); a7 += bfh(x.w);
            u = un;
        }
        if (p + sub8 < end) {
            uint4 x = hp4[(size_t)u * 8 + li8];
            a0 += bfl(x.x); a1 += bfh(x.x);
            a2 += bfl(x.y); a3 += bfh(x.y);
            a4 += bfl(x.z); a5 += bfh(x.z);
            a6 += bfl(x.w); a7 += bfh(x.w);
        }

        #pragma unroll
        for (int m = 8; m <= 32; m <<= 1) {
            a0 += __shfl_xor(a0, m, 64);
            a1 += __shfl_xor(a1, m, 64);
            a2 += __shfl_xor(a2, m, 64);
            a3 += __shfl_xor(a3, m, 64);
            a4 += __shfl_xor(a4, m, 64);
            a5 += __shfl_xor(a5, m, 64);
            a6 += __shfl_xor(a6, m, 64);
            a7 += __shfl_xor(a7, m, 64);
        }

        if (sub8 == 0) {
            const float r = rdeg[v];
            uint4 o;
            o.x = f2bf(a0 * r) | (f2bf(a1 * r) << 16);
            o.y = f2bf(a2 * r) | (f2bf(a3 * r) << 16);
            o.z = f2bf(a4 * r) | (f2bf(a5 * r) << 16);
            o.w = f2bf(a6 * r) | (f2bf(a7 * r) << 16);
            *(uint4*)&M2[wv * 8 + j][li8 * 8] = o;
        }
    }
    __syncthreads();

    // ---- phase 2: out = mean2 + h @ Ws2 + b2 (waves 0..2 handle mt 0..2) ----
    if (wv < 3) {
        const int quad = lane >> 4;
        const int nn   = lane & 15;
        const size_t r0 = (size_t)(base + nn) * F;
        const size_t r1 = (size_t)(base + 16 + nn) * F;

        v4f acc[2];
        acc[0] = (v4f)0.f; acc[1] = (v4f)0.f;

        #pragma unroll
        for (int kt = 0; kt < 4; ++kt) {
            const int koff = kt * 32 + quad * 8;
            v8s b0 = *(const v8s*)(h + r0 + koff);
            v8s b1 = *(const v8s*)(h + r1 + koff);
            v8s a = *(const v8s*)(wfrag + ((size_t)(wv * 4 + kt) * 64 + lane) * 8);
            acc[0] = __builtin_amdgcn_mfma_f32_16x16x32_bf16(a, b0, acc[0], 0, 0, 0);
            acc[1] = __builtin_amdgcn_mfma_f32_16x16x32_bf16(a, b1, acc[1], 0, 0, 0);
        }

        const int m0 = wv * 16 + quad * 4;   // 0..47, multiple of 4
        #pragma unroll
        for (int nt = 0; nt < 2; ++nt) {
            const int node = base + nt * 16 + nn;
            v4f a = acc[nt];
            uint2 mv = *(const uint2*)&M2[nt * 16 + nn][m0];
            float mf[4] = { bfl(mv.x), bfh(mv.x), bfl(mv.y), bfh(mv.y) };
            #pragma unroll
            for (int r = 0; r < 4; ++r) {
                int m = m0 + r;
                if (m < N_CLASSES)
                    out[(size_t)node * N_CLASSES + m] = a[r] + bias[m] + mf[r];
            }
        }
    }
}

// ---------------- launch ----------------

extern "C" void kernel_launch(void* const* d_in, const int* in_sizes, int n_in,
                              void* d_out, int out_size, void* d_ws, size_t ws_size,
                              hipStream_t stream) {
    const float* embed = (const float*)d_in[0];
    const float* Ws0   = (const float*)d_in[1];
    const float* Wn0   = (const float*)d_in[2];
    const float* b0    = (const float*)d_in[3];
    const float* Ws1   = (const float*)d_in[4];
    const float* Wn1   = (const float*)d_in[5];
    const float* b1    = (const float*)d_in[6];
    const float* Ws2   = (const float*)d_in[7];
    const float* Wn2   = (const float*)d_in[8];
    const float* b2    = (const float*)d_in[9];
    const int* input_nodes = (const int*)d_in[10];
    const int* src     = (const int*)d_in[11];
    const int* dst     = (const int*)d_in[12];
    float* out = (float*)d_out;

    char* ws = (char*)d_ws;
    size_t off = 0;
    auto alloc = [&](size_t bytes) -> void* {
        void* p = ws + off;
        off += (bytes + 255) & ~(size_t)255;
        return p;
    };
    int*            fillc    = (int*)           alloc(sizeof(int)   * N_NODES);
    float*          rdeg     = (float*)         alloc(sizeof(float) * N_NODES);
    int*            col      = (int*)           alloc(sizeof(int)   * (size_t)N_NODES * CAP);
    int*            gcnt     = (int*)           alloc(sizeof(int)   * NBKT);
    int2*           staged   = (int2*)          alloc(sizeof(int2)  * (size_t)NBKT * BCAP);
    unsigned short* h_a      = (unsigned short*)alloc(2 * (size_t)N_NODES * F);
    unsigned short* h_b      = (unsigned short*)alloc(2 * (size_t)N_NODES * F);
    unsigned short* hn2      = (unsigned short*)alloc(2 * (size_t)N_NODES * 64);
    unsigned short* wf0      = (unsigned short*)alloc(2 * 64 * 512);
    unsigned short* wf1      = (unsigned short*)alloc(2 * 64 * 512);
    unsigned short* wf2n     = (unsigned short*)alloc(2 * 12 * 512);
    unsigned short* wf2s     = (unsigned short*)alloc(2 * 12 * 512);
    (void)ws_size; (void)n_in; (void)in_sizes; (void)out_size;

    hipMemsetAsync(gcnt, 0, sizeof(int) * NBKT, stream);

    // partition + embed gather in one dispatch
    prologue1_kernel<<<PART_B + EMB_B, PART_T, 0, stream>>>(
        src, dst, gcnt, staged, embed, input_nodes, h_a);
    // scatter + weight pack in one dispatch
    prologue2_kernel<<<NBKT + PACK_B, 512, 0, stream>>>(
        staged, gcnt, fillc, rdeg, col,
        Wn0, Ws0, Wn1, Ws1, Wn2, Ws2, wf0, wf1, wf2n, wf2s);

    const int FUSED_B = N_NODES / 32;        // 3125, exact
    const int GEMM_B  = (N_NODES + 127) / 128;

    // layer 0: h_a -> h_b (fused aggregate + GEMM)
    fused_layer_kernel<<<FUSED_B, 256, 0, stream>>>(h_a, fillc, col, rdeg, wf0, b0, h_b);
    // layer 1: h_b -> h_a
    fused_layer_kernel<<<FUSED_B, 256, 0, stream>>>(h_b, fillc, col, rdeg, wf1, b1, h_a);
    // layer 2 (transform-first): hn2 = h_a @ Wn2 (row stride 64)
    gemm_hn2_kernel<<<GEMM_B, 256, 0, stream>>>(h_a, wf2n, hn2);
    // fused: mean2 = agg48(hn2) in LDS; out = mean2 + h_a @ Ws2 + b2
    fused_final_kernel<<<FUSED_B, 256, 0, stream>>>(hn2, fillc, col, rdeg, h_a, wf2s, b2, out);
}